// Round 13
// baseline (633.906 us; speedup 1.0000x reference)
//
#include <hip/hip_runtime.h>
#include <hip/hip_bf16.h>

typedef __attribute__((ext_vector_type(8))) short bf16x8;
typedef __attribute__((ext_vector_type(4))) float f32x4;

constexpr int D = 128;
constexpr int R = 8;
constexpr float BN_EPS = 1e-5f;

__device__ __forceinline__ unsigned short f2bf(float x) {
  __hip_bfloat16 b = __float2bfloat16(x);
  union { __hip_bfloat16 b; unsigned short u; } c; c.b = b; return c.u;
}
__device__ __forceinline__ float bf2f(unsigned short u) {
  union { float f; unsigned int i; } c; c.i = ((unsigned int)u) << 16; return c.f;
}
__device__ __forceinline__ int swz(int c) {
  return (c >> 3) * 32 + (c & 3) * 8 + ((c >> 2) & 1) * 4;
}

// ---------------------------------------------------------------------------
// Counting sort of edges by key = dst*8 + rel (structure shared by both layers)
// ---------------------------------------------------------------------------
__global__ __launch_bounds__(256) void hist_k(const int* __restrict__ ei,
                                              const int* __restrict__ et,
                                              int* __restrict__ cnt, int E) {
  int e = blockIdx.x * 256 + threadIdx.x;
  if (e >= E) return;
  atomicAdd(&cnt[ei[E + e] * 8 + et[e]], 1);
}

__global__ __launch_bounds__(256) void scan_partial_k(const int* __restrict__ cnt,
                                                      int* __restrict__ offs,
                                                      int* __restrict__ bsum, int NK) {
  __shared__ int s[256];
  int tid = threadIdx.x;
  int base = blockIdx.x * 4096 + tid * 16;
  int loc[16];
  int sum = 0;
  #pragma unroll
  for (int i = 0; i < 16; ++i) {
    int idx = base + i;
    int v = (idx < NK) ? cnt[idx] : 0;
    loc[i] = sum; sum += v;
  }
  s[tid] = sum;
  __syncthreads();
  if (tid == 0) {
    int run = 0;
    for (int i = 0; i < 256; ++i) { int t = s[i]; s[i] = run; run += t; }
    bsum[blockIdx.x] = run;
  }
  __syncthreads();
  int off = s[tid];
  #pragma unroll
  for (int i = 0; i < 16; ++i) {
    int idx = base + i;
    if (idx < NK) offs[idx] = off + loc[i];
  }
}

// single-wave shfl scan
__global__ void scan_bsums_k(int* __restrict__ bsum, int nb) {
  int lane = threadIdx.x;   // 64 threads
  int carry = 0;
  for (int base = 0; base < nb; base += 64) {
    int i = base + lane;
    int orig = (i < nb) ? bsum[i] : 0;
    int v = orig;
    #pragma unroll
    for (int d = 1; d < 64; d <<= 1) {
      int t = __shfl_up(v, d, 64);
      if (lane >= d) v += t;
    }
    if (i < nb) bsum[i] = (v - orig) + carry;   // exclusive + carry
    carry += __shfl(v, 63, 64);
  }
}

__global__ __launch_bounds__(256) void scan_addback_k(int* __restrict__ offs,
                                                      const int* __restrict__ bsum,
                                                      int NK, int E) {
  int idx = blockIdx.x * 256 + threadIdx.x;
  if (idx < NK) offs[idx] += bsum[idx >> 12];
  if (idx == 0) offs[NK] = E;
}

// place: pre-gather (e, src); atomicSub leaves cnt at 0 (no 2nd memset needed)
__global__ __launch_bounds__(256) void place_k(const int* __restrict__ ei,
                                               const int* __restrict__ et,
                                               const int* __restrict__ offs,
                                               int* __restrict__ cnt,
                                               int2* __restrict__ pairs, int E) {
  int e = blockIdx.x * 256 + threadIdx.x;
  if (e >= E) return;
  int key = ei[E + e] * 8 + et[e];
  int pos = offs[key] + atomicSub(&cnt[key], 1) - 1;
  pairs[pos] = make_int2(e, ei[e]);
}

// ---------------------------------------------------------------------------
// BN prep: reduce per-block colstats slots -> per-channel scale/shift
// ---------------------------------------------------------------------------
__global__ void bnprep_k(const float* __restrict__ cst,   // [nblk][256]
                         const float* __restrict__ gamma,
                         const float* __restrict__ beta,
                         float* __restrict__ sc, float* __restrict__ sh,
                         int N, int nblk) {
  int c = threadIdx.x;   // 128 threads
  float s = 0.f, q = 0.f;
  for (int b = 0; b < nblk; ++b) {
    s += cst[b * 256 + c];
    q += cst[b * 256 + 128 + c];
  }
  float invN = 1.0f / (float)N;
  float mu = s * invN;
  float var = q * invN - mu * mu;
  float scale = rsqrtf(var + BN_EPS) * gamma[c];
  sc[c] = scale;
  sh[c] = beta[c] - mu * scale;
}

// ---------------------------------------------------------------------------
// Segment mean: each 32-lane group owns EIGHT consecutive (dst,rel) segments.
// xe gathered fp32 NON-TEMPORAL; h gathered from bf16 swizzled hb.
// Output: Mb [NK][128] bf16, k-swizzled per 32-channel tile for MFMA frags.
// ---------------------------------------------------------------------------
__device__ __forceinline__ void edge_acc(float4& acc, int e, int s, int c, int pos,
                                         const unsigned short* __restrict__ hb,
                                         const float* __restrict__ xe) {
  f32x4 xv = __builtin_nontemporal_load(((const f32x4*)xe) + (size_t)e * 32 + c);
  ushort4 hu = *(const ushort4*)(hb + (size_t)s * 128 + pos);
  acc.x += fmaxf(xv.x + bf2f(hu.x), 0.f);
  acc.y += fmaxf(xv.y + bf2f(hu.y), 0.f);
  acc.z += fmaxf(xv.z + bf2f(hu.z), 0.f);
  acc.w += fmaxf(xv.w + bf2f(hu.w), 0.f);
}

__global__ __launch_bounds__(256) void agg_k(const unsigned short* __restrict__ hb,
                                             const float* __restrict__ xe,
                                             const int2* __restrict__ pairs,
                                             const int* __restrict__ offs,
                                             unsigned short* __restrict__ Mb,
                                             int NK, int rev) {
  int grp = threadIdx.x >> 5;
  int idx = blockIdx.x * 8 + grp;
  int nIdx = NK >> 3;
  if (idx >= nIdx) return;
  if (rev) idx = nIdx - 1 - idx;
  int s0 = idx * 8;
  int c = threadIdx.x & 31;
  int pos = swz(c);

  int4 ov0 = *(const int4*)(offs + s0);       // 32B-aligned
  int4 ov1 = *(const int4*)(offs + s0 + 4);
  int o8 = offs[s0 + 8];
  int st[8] = {ov0.x, ov0.y, ov0.z, ov0.w, ov1.x, ov1.y, ov1.z, ov1.w};
  int en[8] = {ov0.y, ov0.z, ov0.w, ov1.x, ov1.y, ov1.z, ov1.w, o8};

  // issue all 8 pairs loads up front (independent)
  int2 pr[8];
  #pragma unroll
  for (int j = 0; j < 8; ++j) {
    int m = en[j] - st[j];
    if (m > 0) pr[j] = pairs[st[j] + min(c, min(m, 32) - 1)];
  }

  float4 acc[8];
  #pragma unroll
  for (int j = 0; j < 8; ++j) acc[j] = make_float4(0.f, 0.f, 0.f, 0.f);

#define EP(j, i) edge_acc(acc[j], __shfl(pr[j].x, (i), 32), \
                          __shfl(pr[j].y, (i), 32), c, pos, hb, xe)

  #pragma unroll
  for (int j = 0; j < 8; ++j) {
    int m = en[j] - st[j];
    if (m > 0) {
      int mm = min(m, 32);
      EP(j, 0);
      if (mm >= 2) EP(j, 1);
      if (mm >= 3) EP(j, 2);
      if (mm >= 4) EP(j, 3);
      for (int i = 4; i < mm; ++i) EP(j, i);
      // rare: segments longer than 32
      for (int base = st[j] + 32; base < en[j]; base += 32) {
        int mm2 = min(32, en[j] - base);
        int2 pr2 = pairs[base + min(c, mm2 - 1)];
        for (int i = 0; i < mm2; ++i)
          edge_acc(acc[j], __shfl(pr2.x, i, 32), __shfl(pr2.y, i, 32),
                   c, pos, hb, xe);
      }
    }
  }
#undef EP

  #pragma unroll
  for (int j = 0; j < 8; ++j) {
    int len = en[j] - st[j];
    float inv = (len > 0) ? 1.0f / (float)len : 0.f;
    ushort4 u;
    u.x = f2bf(acc[j].x * inv); u.y = f2bf(acc[j].y * inv);
    u.z = f2bf(acc[j].z * inv); u.w = f2bf(acc[j].w * inv);
    *(ushort4*)(Mb + (size_t)(s0 + j) * 128 + pos) = u;
  }
}

// cast fp32 [N,128] -> bf16 swizzled [N,128]; AFF: apply affine + relu first
template <int AFF>
__global__ __launch_bounds__(256) void cast_swz_k(const float* __restrict__ in,
                                                  unsigned short* __restrict__ outb,
                                                  const float* __restrict__ sc,
                                                  const float* __restrict__ sh,
                                                  int n4) {
  int gi = blockIdx.x * 256 + threadIdx.x;
  if (gi >= n4) return;
  int n = gi >> 5, c = gi & 31;
  float4 v = ((const float4*)in)[gi];
  if (AFF) {
    float4 scv = *(const float4*)(sc + c * 4);
    float4 shv = *(const float4*)(sh + c * 4);
    v.x = fmaxf(fmaf(v.x, scv.x, shv.x), 0.f);
    v.y = fmaxf(fmaf(v.y, scv.y, shv.y), 0.f);
    v.z = fmaxf(fmaf(v.z, scv.z, shv.z), 0.f);
    v.w = fmaxf(fmaf(v.w, scv.w, shv.w), 0.f);
  }
  int pos = swz(c);
  ushort4 u;
  u.x = f2bf(v.x); u.y = f2bf(v.y); u.z = f2bf(v.z); u.w = f2bf(v.w);
  *(ushort4*)(outb + (size_t)n * 128 + pos) = u;
}

// W[1152,128] (weight_l | root_l) -> transposed [col][1152], k-swizzled, bf16
__global__ __launch_bounds__(256) void wcast_k(const float* __restrict__ W,
                                               const float* __restrict__ root,
                                               unsigned short* __restrict__ Whi) {
  int idx = blockIdx.x * 256 + threadIdx.x;   // 1152*128 = 147456
  if (idx >= 1152 * 128) return;
  int k = idx >> 7, col = idx & 127;
  float w = (k < 1024) ? W[idx] : root[idx - 1024 * 128];
  int kk = k & 31;
  int pos = (k & ~31) + ((kk & 15) >> 2) * 8 + (kk >> 4) * 4 + (kk & 3);
  Whi[col * 1152 + pos] = f2bf(w);
}

// ---------------------------------------------------------------------------
// MFMA GEMM: out[n,o] = sum_k A[n,k] * W[k,o] + bias[o]
// 256 thr = 4 waves. Block: 128 rows. Wave wv: cols [wv*32, wv*32+32), rf=8.
// rev: process blocks in reverse row order (L3 locality with agg write order).
// BN column stats: each wave owns distinct cols -> direct per-block slot
// writes (no LDS, no barrier, no atomics, no memset needed).
// ---------------------------------------------------------------------------
__global__ __launch_bounds__(256) void gemm_k(
    const unsigned short* __restrict__ Mb,   // [N,1024] swz
    const unsigned short* __restrict__ hb,   // [N,128] swz
    const unsigned short* __restrict__ Whi,  // [128 cols][1152] swz-k
    const float* __restrict__ bias,
    float* __restrict__ out,
    float* __restrict__ cst,                 // [nblk][256]
    int N, int rev) {
  const int tid = threadIdx.x;
  const int wv = tid >> 6, lane = tid & 63;
  const int lr = lane & 15, g = lane >> 4;
  const int bid = rev ? (gridDim.x - 1 - blockIdx.x) : blockIdx.x;
  const int r0 = bid * 128;
  const int cf0 = wv * 2;

  int row[8];
  #pragma unroll
  for (int rf = 0; rf < 8; ++rf) row[rf] = min(r0 + rf * 16 + lr, N - 1);

  const unsigned short* pb0 = Whi + (size_t)(cf0 * 16 + lr) * 1152 + g * 8;
  const unsigned short* pb1 = pb0 + 16 * 1152;

  f32x4 acc[8][2];
  #pragma unroll
  for (int a = 0; a < 8; ++a)
    #pragma unroll
    for (int b = 0; b < 2; ++b) acc[a][b] = (f32x4){0.f, 0.f, 0.f, 0.f};

  // K over Mb: 32 tiles of 32
  #pragma unroll 2
  for (int t = 0; t < 32; ++t) {
    bf16x8 b0 = *(const bf16x8*)(pb0 + t * 32);
    bf16x8 b1 = *(const bf16x8*)(pb1 + t * 32);
    #pragma unroll
    for (int rf = 0; rf < 8; ++rf) {
      bf16x8 a = *(const bf16x8*)(Mb + (size_t)row[rf] * 1024 + t * 32 + g * 8);
      acc[rf][0] = __builtin_amdgcn_mfma_f32_16x16x32_bf16(a, b0, acc[rf][0], 0, 0, 0);
      acc[rf][1] = __builtin_amdgcn_mfma_f32_16x16x32_bf16(a, b1, acc[rf][1], 0, 0, 0);
    }
  }
  // K over hb: 4 tiles of 32
  #pragma unroll
  for (int tt = 0; tt < 4; ++tt) {
    bf16x8 b0 = *(const bf16x8*)(pb0 + 1024 + tt * 32);
    bf16x8 b1 = *(const bf16x8*)(pb1 + 1024 + tt * 32);
    #pragma unroll
    for (int rf = 0; rf < 8; ++rf) {
      bf16x8 a = *(const bf16x8*)(hb + (size_t)row[rf] * 128 + tt * 32 + g * 8);
      acc[rf][0] = __builtin_amdgcn_mfma_f32_16x16x32_bf16(a, b0, acc[rf][0], 0, 0, 0);
      acc[rf][1] = __builtin_amdgcn_mfma_f32_16x16x32_bf16(a, b1, acc[rf][1], 0, 0, 0);
    }
  }

  // epilogue: bias, store, per-block BN column stats
  #pragma unroll
  for (int c = 0; c < 2; ++c) {
    int col = (cf0 + c) * 16 + lr;
    float bs = bias[col];
    float s = 0.f, q = 0.f;
    #pragma unroll
    for (int rf = 0; rf < 8; ++rf) {
      #pragma unroll
      for (int j = 0; j < 4; ++j) {
        int r = r0 + rf * 16 + g * 4 + j;
        if (r < N) {
          float v = acc[rf][c][j] + bs;
          out[(size_t)r * 128 + col] = v;
          s += v; q += v * v;
        }
      }
    }
    s += __shfl_xor(s, 16); s += __shfl_xor(s, 32);
    q += __shfl_xor(q, 16); q += __shfl_xor(q, 32);
    if (g == 0) {
      cst[(size_t)blockIdx.x * 256 + col] = s;
      cst[(size_t)blockIdx.x * 256 + 128 + col] = q;
    }
  }
}

// ---------------------------------------------------------------------------
// BN apply (final layer only, no relu): pure affine with precomputed sc/sh
// ---------------------------------------------------------------------------
__global__ __launch_bounds__(256) void bn_apply_k(
    const float* __restrict__ in, float* __restrict__ out,
    const float* __restrict__ sc, const float* __restrict__ sh, int N) {
  int gi = blockIdx.x * 256 + threadIdx.x;
  if (gi >= N * 32) return;
  int c0 = (gi & 31) * 4;
  float4 v = ((const float4*)in)[gi];
  float4 scv = *(const float4*)(sc + c0);
  float4 shv = *(const float4*)(sh + c0);
  float4 o;
  o.x = fmaf(v.x, scv.x, shv.x);
  o.y = fmaf(v.y, scv.y, shv.y);
  o.z = fmaf(v.z, scv.z, shv.z);
  o.w = fmaf(v.w, scv.w, shv.w);
  ((float4*)out)[gi] = o;
}

extern "C" void kernel_launch(void* const* d_in, const int* in_sizes, int n_in,
                              void* d_out, int out_size, void* d_ws, size_t ws_size,
                              hipStream_t stream) {
  const float* x      = (const float*)d_in[0];
  const float* xe     = (const float*)d_in[1];
  const int*   ei     = (const int*)d_in[2];
  const int*   et     = (const int*)d_in[3];
  const float* weight = (const float*)d_in[4];
  const float* root   = (const float*)d_in[5];
  const float* bias   = (const float*)d_in[6];
  const float* gamma  = (const float*)d_in[7];
  const float* beta   = (const float*)d_in[8];
  float* out = (float*)d_out;

  const int N = in_sizes[0] / D;   // 50000
  const int E = in_sizes[3];       // 500000
  const int NK = N * R;            // 400000

  const int gemmBlocks = (N + 127) / 128;

  // workspace layout (256B-aligned chunks)
  char* w = (char*)d_ws;
  size_t off = 0;
  auto alloc = [&](size_t bytes) { char* p = w + off; off = (off + bytes + 255) & ~(size_t)255; return p; };
  unsigned short* Mb   = (unsigned short*)alloc((size_t)NK * 128 * 2);
  unsigned short* hb   = (unsigned short*)alloc((size_t)N * 128 * 2);
  float*          h1   = (float*)alloc((size_t)N * 128 * 4);
  unsigned short* Whi  = (unsigned short*)alloc(1152 * 128 * 2);
  int*            offs = (int*)alloc((size_t)(NK + 8) * 4);
  int*            cnt  = (int*)alloc((size_t)NK * 4);
  int2*           pairs= (int2*)alloc((size_t)E * 8);
  int*            bsum = (int*)alloc(512 * 4);
  float*          cst0 = (float*)alloc((size_t)gemmBlocks * 256 * 4);
  float*          cst1 = (float*)alloc((size_t)gemmBlocks * 256 * 4);
  float*          sc0  = (float*)alloc(128 * 4);
  float*          sh0  = (float*)alloc(128 * 4);
  float*          sc1  = (float*)alloc(128 * 4);
  float*          sh1  = (float*)alloc(128 * 4);

  const int NB = (NK + 4095) / 4096;

  // --- counting sort (edge structure; shared by both layers) ---
  hipMemsetAsync(cnt, 0, (size_t)NK * 4, stream);
  hist_k<<<(E + 255) / 256, 256, 0, stream>>>(ei, et, cnt, E);
  scan_partial_k<<<NB, 256, 0, stream>>>(cnt, offs, bsum, NK);
  scan_bsums_k<<<1, 64, 0, stream>>>(bsum, NB);
  scan_addback_k<<<(NK + 255) / 256, 256, 0, stream>>>(offs, bsum, NK, E);
  place_k<<<(E + 255) / 256, 256, 0, stream>>>(ei, et, offs, cnt, pairs, E);

  const int aggBlocks  = ((NK >> 3) + 7) / 8;
  const int castBlocks = (N * 32 + 255) / 256;

  // ---- layer 0 (agg forward writes Mb; gemm reversed reads hot tail first) --
  wcast_k<<<576, 256, 0, stream>>>(weight, root, Whi);
  cast_swz_k<0><<<castBlocks, 256, 0, stream>>>(x, hb, nullptr, nullptr, N * 32);
  agg_k<<<aggBlocks, 256, 0, stream>>>(hb, xe, pairs, offs, Mb, NK, 0);
  gemm_k<<<gemmBlocks, 256, 0, stream>>>(Mb, hb, Whi, bias, h1, cst0, N, 1);
  bnprep_k<<<1, 128, 0, stream>>>(cst0, gamma, beta, sc0, sh0, N, gemmBlocks);

  // ---- layer 1 (agg reversed writes Mb head last; gemm forward) ----
  wcast_k<<<576, 256, 0, stream>>>(weight + (size_t)1024 * 128,
                                   root + (size_t)128 * 128, Whi);
  cast_swz_k<1><<<castBlocks, 256, 0, stream>>>(h1, hb, sc0, sh0, N * 32);
  agg_k<<<aggBlocks, 256, 0, stream>>>(hb, xe, pairs, offs, Mb, NK, 1);
  gemm_k<<<gemmBlocks, 256, 0, stream>>>(Mb, hb, Whi, bias + D, out, cst1, N, 0);
  bnprep_k<<<1, 128, 0, stream>>>(cst1, gamma + D, beta + D, sc1, sh1, N, gemmBlocks);
  bn_apply_k<<<castBlocks, 256, 0, stream>>>(out, out, sc1, sh1, N);
}

// Round 14
// 446.962 us; speedup vs baseline: 1.4183x; 1.4183x over previous
//
#include <hip/hip_runtime.h>
#include <hip/hip_bf16.h>

typedef __attribute__((ext_vector_type(8))) short bf16x8;
typedef __attribute__((ext_vector_type(4))) float f32x4;

constexpr int D = 128;
constexpr int R = 8;
constexpr float BN_EPS = 1e-5f;

__device__ __forceinline__ unsigned short f2bf(float x) {
  __hip_bfloat16 b = __float2bfloat16(x);
  union { __hip_bfloat16 b; unsigned short u; } c; c.b = b; return c.u;
}
__device__ __forceinline__ float bf2f(unsigned short u) {
  union { float f; unsigned int i; } c; c.i = ((unsigned int)u) << 16; return c.f;
}
__device__ __forceinline__ int swz(int c) {
  return (c >> 3) * 32 + (c & 3) * 8 + ((c >> 2) & 1) * 4;
}

// ---------------------------------------------------------------------------
// Counting sort of edges by key = dst*8 + rel (structure shared by both layers)
// ---------------------------------------------------------------------------
__global__ __launch_bounds__(256) void hist_k(const int* __restrict__ ei,
                                              const int* __restrict__ et,
                                              int* __restrict__ cnt, int E) {
  int e = blockIdx.x * 256 + threadIdx.x;
  if (e >= E) return;
  atomicAdd(&cnt[ei[E + e] * 8 + et[e]], 1);
}

__global__ __launch_bounds__(256) void scan_partial_k(const int* __restrict__ cnt,
                                                      int* __restrict__ offs,
                                                      int* __restrict__ bsum, int NK) {
  __shared__ int s[256];
  int tid = threadIdx.x;
  int base = blockIdx.x * 4096 + tid * 16;
  int loc[16];
  int sum = 0;
  #pragma unroll
  for (int i = 0; i < 16; ++i) {
    int idx = base + i;
    int v = (idx < NK) ? cnt[idx] : 0;
    loc[i] = sum; sum += v;
  }
  s[tid] = sum;
  __syncthreads();
  if (tid == 0) {
    int run = 0;
    for (int i = 0; i < 256; ++i) { int t = s[i]; s[i] = run; run += t; }
    bsum[blockIdx.x] = run;
  }
  __syncthreads();
  int off = s[tid];
  #pragma unroll
  for (int i = 0; i < 16; ++i) {
    int idx = base + i;
    if (idx < NK) offs[idx] = off + loc[i];
  }
}

// single-wave shfl scan
__global__ void scan_bsums_k(int* __restrict__ bsum, int nb) {
  int lane = threadIdx.x;   // 64 threads
  int carry = 0;
  for (int base = 0; base < nb; base += 64) {
    int i = base + lane;
    int orig = (i < nb) ? bsum[i] : 0;
    int v = orig;
    #pragma unroll
    for (int d = 1; d < 64; d <<= 1) {
      int t = __shfl_up(v, d, 64);
      if (lane >= d) v += t;
    }
    if (i < nb) bsum[i] = (v - orig) + carry;   // exclusive + carry
    carry += __shfl(v, 63, 64);
  }
}

__global__ __launch_bounds__(256) void scan_addback_k(int* __restrict__ offs,
                                                      const int* __restrict__ bsum,
                                                      int NK, int E) {
  int idx = blockIdx.x * 256 + threadIdx.x;
  if (idx < NK) offs[idx] += bsum[idx >> 12];
  if (idx == 0) offs[NK] = E;
}

// place: pre-gather (e, src); atomicSub leaves cnt at 0 (no 2nd memset needed)
__global__ __launch_bounds__(256) void place_k(const int* __restrict__ ei,
                                               const int* __restrict__ et,
                                               const int* __restrict__ offs,
                                               int* __restrict__ cnt,
                                               int2* __restrict__ pairs, int E) {
  int e = blockIdx.x * 256 + threadIdx.x;
  if (e >= E) return;
  int key = ei[E + e] * 8 + et[e];
  int pos = offs[key] + atomicSub(&cnt[key], 1) - 1;
  pairs[pos] = make_int2(e, ei[e]);
}

// ---------------------------------------------------------------------------
// BN prep: PARALLEL reduce of per-block colstats -> per-channel scale/shift.
// grid = 128 (one block per channel), block = 64 lanes; each lane sums a
// stride-64 slice of the nblk slots, then wave shfl reduce.
// ---------------------------------------------------------------------------
__global__ __launch_bounds__(64) void bnprep_k(const float* __restrict__ cst, // [nblk][256]
                                               const float* __restrict__ gamma,
                                               const float* __restrict__ beta,
                                               float* __restrict__ sc,
                                               float* __restrict__ sh,
                                               int N, int nblk) {
  int c = blockIdx.x;      // channel
  int lane = threadIdx.x;  // 64
  float s = 0.f, q = 0.f;
  for (int b = lane; b < nblk; b += 64) {
    s += cst[(size_t)b * 256 + c];
    q += cst[(size_t)b * 256 + 128 + c];
  }
  #pragma unroll
  for (int d = 32; d >= 1; d >>= 1) {
    s += __shfl_xor(s, d, 64);
    q += __shfl_xor(q, d, 64);
  }
  if (lane == 0) {
    float invN = 1.0f / (float)N;
    float mu = s * invN;
    float var = q * invN - mu * mu;
    float scale = rsqrtf(var + BN_EPS) * gamma[c];
    sc[c] = scale;
    sh[c] = beta[c] - mu * scale;
  }
}

// ---------------------------------------------------------------------------
// Segment mean: each 32-lane group owns EIGHT consecutive (dst,rel) segments.
// xe gathered fp32 NON-TEMPORAL; h gathered from bf16 swizzled hb.
// Output: Mb [NK][128] bf16, k-swizzled per 32-channel tile for MFMA frags.
// ---------------------------------------------------------------------------
__device__ __forceinline__ void edge_acc(float4& acc, int e, int s, int c, int pos,
                                         const unsigned short* __restrict__ hb,
                                         const float* __restrict__ xe) {
  f32x4 xv = __builtin_nontemporal_load(((const f32x4*)xe) + (size_t)e * 32 + c);
  ushort4 hu = *(const ushort4*)(hb + (size_t)s * 128 + pos);
  acc.x += fmaxf(xv.x + bf2f(hu.x), 0.f);
  acc.y += fmaxf(xv.y + bf2f(hu.y), 0.f);
  acc.z += fmaxf(xv.z + bf2f(hu.z), 0.f);
  acc.w += fmaxf(xv.w + bf2f(hu.w), 0.f);
}

__global__ __launch_bounds__(256) void agg_k(const unsigned short* __restrict__ hb,
                                             const float* __restrict__ xe,
                                             const int2* __restrict__ pairs,
                                             const int* __restrict__ offs,
                                             unsigned short* __restrict__ Mb,
                                             int NK, int rev) {
  int grp = threadIdx.x >> 5;
  int idx = blockIdx.x * 8 + grp;
  int nIdx = NK >> 3;
  if (idx >= nIdx) return;
  if (rev) idx = nIdx - 1 - idx;
  int s0 = idx * 8;
  int c = threadIdx.x & 31;
  int pos = swz(c);

  int4 ov0 = *(const int4*)(offs + s0);       // 32B-aligned
  int4 ov1 = *(const int4*)(offs + s0 + 4);
  int o8 = offs[s0 + 8];
  int st[8] = {ov0.x, ov0.y, ov0.z, ov0.w, ov1.x, ov1.y, ov1.z, ov1.w};
  int en[8] = {ov0.y, ov0.z, ov0.w, ov1.x, ov1.y, ov1.z, ov1.w, o8};

  // issue all 8 pairs loads up front (independent)
  int2 pr[8];
  #pragma unroll
  for (int j = 0; j < 8; ++j) {
    int m = en[j] - st[j];
    if (m > 0) pr[j] = pairs[st[j] + min(c, min(m, 32) - 1)];
  }

  float4 acc[8];
  #pragma unroll
  for (int j = 0; j < 8; ++j) acc[j] = make_float4(0.f, 0.f, 0.f, 0.f);

#define EP(j, i) edge_acc(acc[j], __shfl(pr[j].x, (i), 32), \
                          __shfl(pr[j].y, (i), 32), c, pos, hb, xe)

  #pragma unroll
  for (int j = 0; j < 8; ++j) {
    int m = en[j] - st[j];
    if (m > 0) {
      int mm = min(m, 32);
      EP(j, 0);
      if (mm >= 2) EP(j, 1);
      if (mm >= 3) EP(j, 2);
      if (mm >= 4) EP(j, 3);
      for (int i = 4; i < mm; ++i) EP(j, i);
      // rare: segments longer than 32
      for (int base = st[j] + 32; base < en[j]; base += 32) {
        int mm2 = min(32, en[j] - base);
        int2 pr2 = pairs[base + min(c, mm2 - 1)];
        for (int i = 0; i < mm2; ++i)
          edge_acc(acc[j], __shfl(pr2.x, i, 32), __shfl(pr2.y, i, 32),
                   c, pos, hb, xe);
      }
    }
  }
#undef EP

  #pragma unroll
  for (int j = 0; j < 8; ++j) {
    int len = en[j] - st[j];
    float inv = (len > 0) ? 1.0f / (float)len : 0.f;
    ushort4 u;
    u.x = f2bf(acc[j].x * inv); u.y = f2bf(acc[j].y * inv);
    u.z = f2bf(acc[j].z * inv); u.w = f2bf(acc[j].w * inv);
    *(ushort4*)(Mb + (size_t)(s0 + j) * 128 + pos) = u;
  }
}

// cast fp32 [N,128] -> bf16 swizzled [N,128]; AFF: apply affine + relu first
template <int AFF>
__global__ __launch_bounds__(256) void cast_swz_k(const float* __restrict__ in,
                                                  unsigned short* __restrict__ outb,
                                                  const float* __restrict__ sc,
                                                  const float* __restrict__ sh,
                                                  int n4) {
  int gi = blockIdx.x * 256 + threadIdx.x;
  if (gi >= n4) return;
  int n = gi >> 5, c = gi & 31;
  float4 v = ((const float4*)in)[gi];
  if (AFF) {
    float4 scv = *(const float4*)(sc + c * 4);
    float4 shv = *(const float4*)(sh + c * 4);
    v.x = fmaxf(fmaf(v.x, scv.x, shv.x), 0.f);
    v.y = fmaxf(fmaf(v.y, scv.y, shv.y), 0.f);
    v.z = fmaxf(fmaf(v.z, scv.z, shv.z), 0.f);
    v.w = fmaxf(fmaf(v.w, scv.w, shv.w), 0.f);
  }
  int pos = swz(c);
  ushort4 u;
  u.x = f2bf(v.x); u.y = f2bf(v.y); u.z = f2bf(v.z); u.w = f2bf(v.w);
  *(ushort4*)(outb + (size_t)n * 128 + pos) = u;
}

// W[1152,128] (weight_l | root_l) -> transposed [col][1152], k-swizzled, bf16
__global__ __launch_bounds__(256) void wcast_k(const float* __restrict__ W,
                                               const float* __restrict__ root,
                                               unsigned short* __restrict__ Whi) {
  int idx = blockIdx.x * 256 + threadIdx.x;   // 1152*128 = 147456
  if (idx >= 1152 * 128) return;
  int k = idx >> 7, col = idx & 127;
  float w = (k < 1024) ? W[idx] : root[idx - 1024 * 128];
  int kk = k & 31;
  int pos = (k & ~31) + ((kk & 15) >> 2) * 8 + (kk >> 4) * 4 + (kk & 3);
  Whi[col * 1152 + pos] = f2bf(w);
}

// ---------------------------------------------------------------------------
// MFMA GEMM: out[n,o] = sum_k A[n,k] * W[k,o] + bias[o]
// 256 thr = 4 waves. Block: 128 rows. Wave wv: cols [wv*32, wv*32+32), rf=8.
// rev: process blocks in reverse row order (L3 locality with agg write order).
// BN column stats: direct per-block slot writes (no LDS/barrier/atomics).
// ---------------------------------------------------------------------------
__global__ __launch_bounds__(256) void gemm_k(
    const unsigned short* __restrict__ Mb,   // [N,1024] swz
    const unsigned short* __restrict__ hb,   // [N,128] swz
    const unsigned short* __restrict__ Whi,  // [128 cols][1152] swz-k
    const float* __restrict__ bias,
    float* __restrict__ out,
    float* __restrict__ cst,                 // [nblk][256]
    int N, int rev) {
  const int tid = threadIdx.x;
  const int wv = tid >> 6, lane = tid & 63;
  const int lr = lane & 15, g = lane >> 4;
  const int bid = rev ? (gridDim.x - 1 - blockIdx.x) : blockIdx.x;
  const int r0 = bid * 128;
  const int cf0 = wv * 2;

  int row[8];
  #pragma unroll
  for (int rf = 0; rf < 8; ++rf) row[rf] = min(r0 + rf * 16 + lr, N - 1);

  const unsigned short* pb0 = Whi + (size_t)(cf0 * 16 + lr) * 1152 + g * 8;
  const unsigned short* pb1 = pb0 + 16 * 1152;

  f32x4 acc[8][2];
  #pragma unroll
  for (int a = 0; a < 8; ++a)
    #pragma unroll
    for (int b = 0; b < 2; ++b) acc[a][b] = (f32x4){0.f, 0.f, 0.f, 0.f};

  // K over Mb: 32 tiles of 32
  #pragma unroll 2
  for (int t = 0; t < 32; ++t) {
    bf16x8 b0 = *(const bf16x8*)(pb0 + t * 32);
    bf16x8 b1 = *(const bf16x8*)(pb1 + t * 32);
    #pragma unroll
    for (int rf = 0; rf < 8; ++rf) {
      bf16x8 a = *(const bf16x8*)(Mb + (size_t)row[rf] * 1024 + t * 32 + g * 8);
      acc[rf][0] = __builtin_amdgcn_mfma_f32_16x16x32_bf16(a, b0, acc[rf][0], 0, 0, 0);
      acc[rf][1] = __builtin_amdgcn_mfma_f32_16x16x32_bf16(a, b1, acc[rf][1], 0, 0, 0);
    }
  }
  // K over hb: 4 tiles of 32
  #pragma unroll
  for (int tt = 0; tt < 4; ++tt) {
    bf16x8 b0 = *(const bf16x8*)(pb0 + 1024 + tt * 32);
    bf16x8 b1 = *(const bf16x8*)(pb1 + 1024 + tt * 32);
    #pragma unroll
    for (int rf = 0; rf < 8; ++rf) {
      bf16x8 a = *(const bf16x8*)(hb + (size_t)row[rf] * 128 + tt * 32 + g * 8);
      acc[rf][0] = __builtin_amdgcn_mfma_f32_16x16x32_bf16(a, b0, acc[rf][0], 0, 0, 0);
      acc[rf][1] = __builtin_amdgcn_mfma_f32_16x16x32_bf16(a, b1, acc[rf][1], 0, 0, 0);
    }
  }

  // epilogue: bias, store, per-block BN column stats
  #pragma unroll
  for (int c = 0; c < 2; ++c) {
    int col = (cf0 + c) * 16 + lr;
    float bs = bias[col];
    float s = 0.f, q = 0.f;
    #pragma unroll
    for (int rf = 0; rf < 8; ++rf) {
      #pragma unroll
      for (int j = 0; j < 4; ++j) {
        int r = r0 + rf * 16 + g * 4 + j;
        if (r < N) {
          float v = acc[rf][c][j] + bs;
          out[(size_t)r * 128 + col] = v;
          s += v; q += v * v;
        }
      }
    }
    s += __shfl_xor(s, 16); s += __shfl_xor(s, 32);
    q += __shfl_xor(q, 16); q += __shfl_xor(q, 32);
    if (g == 0) {
      cst[(size_t)blockIdx.x * 256 + col] = s;
      cst[(size_t)blockIdx.x * 256 + 128 + col] = q;
    }
  }
}

// ---------------------------------------------------------------------------
// BN apply (final layer only, no relu): pure affine with precomputed sc/sh
// ---------------------------------------------------------------------------
__global__ __launch_bounds__(256) void bn_apply_k(
    const float* __restrict__ in, float* __restrict__ out,
    const float* __restrict__ sc, const float* __restrict__ sh, int N) {
  int gi = blockIdx.x * 256 + threadIdx.x;
  if (gi >= N * 32) return;
  int c0 = (gi & 31) * 4;
  float4 v = ((const float4*)in)[gi];
  float4 scv = *(const float4*)(sc + c0);
  float4 shv = *(const float4*)(sh + c0);
  float4 o;
  o.x = fmaf(v.x, scv.x, shv.x);
  o.y = fmaf(v.y, scv.y, shv.y);
  o.z = fmaf(v.z, scv.z, shv.z);
  o.w = fmaf(v.w, scv.w, shv.w);
  ((float4*)out)[gi] = o;
}

extern "C" void kernel_launch(void* const* d_in, const int* in_sizes, int n_in,
                              void* d_out, int out_size, void* d_ws, size_t ws_size,
                              hipStream_t stream) {
  const float* x      = (const float*)d_in[0];
  const float* xe     = (const float*)d_in[1];
  const int*   ei     = (const int*)d_in[2];
  const int*   et     = (const int*)d_in[3];
  const float* weight = (const float*)d_in[4];
  const float* root   = (const float*)d_in[5];
  const float* bias   = (const float*)d_in[6];
  const float* gamma  = (const float*)d_in[7];
  const float* beta   = (const float*)d_in[8];
  float* out = (float*)d_out;

  const int N = in_sizes[0] / D;   // 50000
  const int E = in_sizes[3];       // 500000
  const int NK = N * R;            // 400000

  const int gemmBlocks = (N + 127) / 128;

  // workspace layout (256B-aligned chunks)
  char* w = (char*)d_ws;
  size_t off = 0;
  auto alloc = [&](size_t bytes) { char* p = w + off; off = (off + bytes + 255) & ~(size_t)255; return p; };
  unsigned short* Mb   = (unsigned short*)alloc((size_t)NK * 128 * 2);
  unsigned short* hb   = (unsigned short*)alloc((size_t)N * 128 * 2);
  float*          h1   = (float*)alloc((size_t)N * 128 * 4);
  unsigned short* Whi  = (unsigned short*)alloc(1152 * 128 * 2);
  int*            offs = (int*)alloc((size_t)(NK + 8) * 4);
  int*            cnt  = (int*)alloc((size_t)NK * 4);
  int2*           pairs= (int2*)alloc((size_t)E * 8);
  int*            bsum = (int*)alloc(512 * 4);
  float*          cst0 = (float*)alloc((size_t)gemmBlocks * 256 * 4);
  float*          cst1 = (float*)alloc((size_t)gemmBlocks * 256 * 4);
  float*          sc0  = (float*)alloc(128 * 4);
  float*          sh0  = (float*)alloc(128 * 4);
  float*          sc1  = (float*)alloc(128 * 4);
  float*          sh1  = (float*)alloc(128 * 4);

  const int NB = (NK + 4095) / 4096;

  // --- counting sort (edge structure; shared by both layers) ---
  hipMemsetAsync(cnt, 0, (size_t)NK * 4, stream);
  hist_k<<<(E + 255) / 256, 256, 0, stream>>>(ei, et, cnt, E);
  scan_partial_k<<<NB, 256, 0, stream>>>(cnt, offs, bsum, NK);
  scan_bsums_k<<<1, 64, 0, stream>>>(bsum, NB);
  scan_addback_k<<<(NK + 255) / 256, 256, 0, stream>>>(offs, bsum, NK, E);
  place_k<<<(E + 255) / 256, 256, 0, stream>>>(ei, et, offs, cnt, pairs, E);

  const int aggBlocks  = ((NK >> 3) + 7) / 8;
  const int castBlocks = (N * 32 + 255) / 256;

  // ---- layer 0 (agg forward writes Mb; gemm reversed reads hot tail first) --
  wcast_k<<<576, 256, 0, stream>>>(weight, root, Whi);
  cast_swz_k<0><<<castBlocks, 256, 0, stream>>>(x, hb, nullptr, nullptr, N * 32);
  agg_k<<<aggBlocks, 256, 0, stream>>>(hb, xe, pairs, offs, Mb, NK, 0);
  gemm_k<<<gemmBlocks, 256, 0, stream>>>(Mb, hb, Whi, bias, h1, cst0, N, 1);
  bnprep_k<<<128, 64, 0, stream>>>(cst0, gamma, beta, sc0, sh0, N, gemmBlocks);

  // ---- layer 1 (agg reversed writes Mb head last; gemm forward) ----
  wcast_k<<<576, 256, 0, stream>>>(weight + (size_t)1024 * 128,
                                   root + (size_t)128 * 128, Whi);
  cast_swz_k<1><<<castBlocks, 256, 0, stream>>>(h1, hb, sc0, sh0, N * 32);
  agg_k<<<aggBlocks, 256, 0, stream>>>(hb, xe, pairs, offs, Mb, NK, 1);
  gemm_k<<<gemmBlocks, 256, 0, stream>>>(Mb, hb, Whi, bias + D, out, cst1, N, 0);
  bnprep_k<<<128, 64, 0, stream>>>(cst1, gamma + D, beta + D, sc1, sh1, N, gemmBlocks);
  bn_apply_k<<<castBlocks, 256, 0, stream>>>(out, out, sc1, sh1, N);
}